// Round 2
// baseline (395.026 us; speedup 1.0000x reference)
//
#include <hip/hip_runtime.h>
#include <math.h>

// BasicBlockA: masked conv (L*C out) + bias + ELU -> grouped masked conv -> mean over L + residual.
// Fully fused: one block = one 32x32 output tile of one batch image.
// Mask analysis: kernel row ky=2 is always zero; row ky=1 keeps kx=0 always and kx=1 iff j<=i.
// R2: stage-1 x neighborhood cached in registers across the latent loop (was: LDS re-read
// per latent -> 2.1e7 bank-conflict cycles); boundary masks precomputed as float 0/1.

namespace {
constexpr int NC = 3, NH = 128, NW = 128, NL = 16;
constexpr int TILE = 32;
constexpr int XR = 34, XC = 40;  // x tile: rows (oy0-2 .. oy0+31), 40-col stride, 3ch interleaved
constexpr int HR = 33, HC = 36;  // h tile: rows (oy0-1 .. oy0+31), 36-col stride, 3ch interleaved
constexpr int WPL = 54;          // packed weights per latent: [i][j][ky<2][kx<3]
}

__device__ __forceinline__ float softplusf(float v) {
    return v > 20.f ? v : log1pf(expf(v));
}

// Build masked weights into d_ws: wb[0..863] = w1 packed, wb[864..1727] = w2 packed.
// Packed layout [l][i][j][ky(2)][kx(3)]; the always-masked ky==2 row is dropped.
__global__ void prep_weights(const float* __restrict__ w1, const float* __restrict__ c1,
                             const float* __restrict__ w2, const float* __restrict__ c2,
                             float* __restrict__ wb) {
    int e = blockIdx.x * blockDim.x + threadIdx.x;
    if (e >= NL * NC * NC * 2 * 3) return;
    int kx = e % 3;
    int ky = (e / 3) % 2;
    int j  = (e / 6) % 3;
    int i  = (e / 18) % 3;
    int l  = e / WPL;
    int g = l * 81 + i * 27 + j * 9 + ky * 3 + kx;  // [L,C,C,3,3] global index
    bool used   = (ky == 0) || (kx == 0) || (kx == 1 && j <= i);
    bool center = (i == j) && (ky == 1) && (kx == 1);
    wb[e]       = used ? (center ? softplusf(c1[g]) : w1[g]) : 0.f;
    wb[864 + e] = used ? (center ? softplusf(c2[g]) : w2[g]) : 0.f;
}

__device__ __forceinline__ float eluf(float v) {
    float e = __expf(v) - 1.f;
    return v > 0.f ? v : e;
}

__global__ __launch_bounds__(256, 4) void fused_block(
    const float* __restrict__ x, const float* __restrict__ bias1,
    const float* __restrict__ res, const float* __restrict__ wb,
    float* __restrict__ out)
{
    __shared__ alignas(16) float xs[XR * XC * 3];
    __shared__ alignas(16) float hs[HR * HC * 3];

    const int tid = threadIdx.x;
    const int b   = blockIdx.z;
    const int oy0 = blockIdx.y * TILE;
    const int ox0 = blockIdx.x * TILE;

    // ---- load x tile: planar (coalesced) global reads, channel-interleaved LDS store ----
    const float* xb = x + b * NC * NH * NW;
    for (int idx = tid; idx < XR * XC * 3; idx += 256) {
        int lx = idx % XC;
        int ly = (idx / XC) % XR;
        int c  = idx / (XC * XR);
        int gy = oy0 - 2 + ly, gx = ox0 - 2 + lx;
        float v = 0.f;
        if (gy >= 0 && gy < NH && gx >= 0 && gx < NW)
            v = xb[c * NH * NW + gy * NW + gx];
        xs[(ly * XC + lx) * 3 + c] = v;
    }
    __syncthreads();

    // ---- chunk assignment: A = chk tid (all threads), B = chk tid+256 (tid<41) ----
    const int rA  = tid / 9;          // h row 0..28 for tid<261 -> 0..28; tid 0..255 -> r 0..28
    const int uA  = tid % 9;
    const int cA  = uA * 4;
    const bool hasB = (tid < HR * 9 - 256);   // 41 threads
    const int rB  = (tid + 256) / 9;
    const int cB  = ((tid + 256) % 9) * 4;

    // register-cache chunk A's x neighborhood (rows rA, rA+1): row0 18 floats, row1 16
    float xa0[18], xa1[16];
    {
        const float* p0 = &xs[(rA * XC + cA) * 3];
        const float* p1 = &xs[((rA + 1) * XC + cA) * 3];
        float4 a0 = ((const float4*)p0)[0], a1 = ((const float4*)p0)[1];
        float4 a2 = ((const float4*)p0)[2], a3 = ((const float4*)p0)[3];
        float2 a4 = ((const float2*)p0)[8];
        xa0[0]=a0.x; xa0[1]=a0.y; xa0[2]=a0.z; xa0[3]=a0.w;
        xa0[4]=a1.x; xa0[5]=a1.y; xa0[6]=a1.z; xa0[7]=a1.w;
        xa0[8]=a2.x; xa0[9]=a2.y; xa0[10]=a2.z; xa0[11]=a2.w;
        xa0[12]=a3.x; xa0[13]=a3.y; xa0[14]=a3.z; xa0[15]=a3.w;
        xa0[16]=a4.x; xa0[17]=a4.y;
        float4 b0 = ((const float4*)p1)[0], b1 = ((const float4*)p1)[1];
        float4 b2 = ((const float4*)p1)[2], b3 = ((const float4*)p1)[3];
        xa1[0]=b0.x; xa1[1]=b0.y; xa1[2]=b0.z; xa1[3]=b0.w;
        xa1[4]=b1.x; xa1[5]=b1.y; xa1[6]=b1.z; xa1[7]=b1.w;
        xa1[8]=b2.x; xa1[9]=b2.y; xa1[10]=b2.z; xa1[11]=b2.w;
        xa1[12]=b3.x; xa1[13]=b3.y; xa1[14]=b3.z; xa1[15]=b3.w;
    }
    // boundary masks (float 0/1), precomputed once
    float mA[4], mB[4];
    {
        int gyA = oy0 - 1 + rA;
        bool ra = (gyA >= 0 && gyA < NH);
        int gyB = oy0 - 1 + rB;
        bool rb = (gyB >= 0 && gyB < NH);
        #pragma unroll
        for (int p = 0; p < 4; ++p) {
            int gxA = ox0 - 1 + cA + p;
            mA[p] = (ra && gxA >= 0 && gxA < NW) ? 1.f : 0.f;
            int gxB = ox0 - 1 + cB + p;
            mB[p] = (rb && gxB >= 0 && gxB < NW) ? 1.f : 0.f;
        }
    }

    const int ty = tid >> 3;       // output row within tile (0..31)
    const int tx = (tid & 7) * 4;  // output col, 1x4 chunk per thread
    float acc[3][4] = {{0.f}};

    #pragma unroll 1
    for (int l = 0; l < NL; ++l) {
        // stage-1 weights (uniform -> scalar loads); only live taps used
        float w1r[3][3][2][3];
        #pragma unroll
        for (int i = 0; i < 3; ++i)
        #pragma unroll
        for (int j = 0; j < 3; ++j)
        #pragma unroll
        for (int ky = 0; ky < 2; ++ky)
        #pragma unroll
        for (int kx = 0; kx < 3; ++kx)
            if (ky == 0 || kx == 0 || (kx == 1 && j <= i))
                w1r[i][j][ky][kx] = wb[l * WPL + i * 18 + j * 6 + ky * 3 + kx];
        float br[3];
        #pragma unroll
        for (int i = 0; i < 3; ++i) br[i] = bias1[l * 3 + i];

        __syncthreads();  // prev latent's stage-2 reads done -> hs writable

        // ---- stage 1, chunk A: registers only ----
        {
            float pre[3][4];
            #pragma unroll
            for (int i = 0; i < 3; ++i)
                #pragma unroll
                for (int p = 0; p < 4; ++p) pre[i][p] = br[i];
            #pragma unroll
            for (int i = 0; i < 3; ++i)
            #pragma unroll
            for (int j = 0; j < 3; ++j)
            #pragma unroll
            for (int kx = 0; kx < 3; ++kx) {
                float w0 = w1r[i][j][0][kx];
                #pragma unroll
                for (int p = 0; p < 4; ++p)
                    pre[i][p] += w0 * xa0[(kx + p) * 3 + j];
                if (kx == 0 || (kx == 1 && j <= i)) {
                    float w1v = w1r[i][j][1][kx];
                    #pragma unroll
                    for (int p = 0; p < 4; ++p)
                        pre[i][p] += w1v * xa1[(kx + p) * 3 + j];
                }
            }
            float hv[12];
            #pragma unroll
            for (int p = 0; p < 4; ++p)
                #pragma unroll
                for (int i = 0; i < 3; ++i)
                    hv[p * 3 + i] = eluf(pre[i][p]) * mA[p];
            float* hrow = &hs[(rA * HC + cA) * 3];
            ((float4*)hrow)[0] = make_float4(hv[0], hv[1], hv[2],  hv[3]);
            ((float4*)hrow)[1] = make_float4(hv[4], hv[5], hv[6],  hv[7]);
            ((float4*)hrow)[2] = make_float4(hv[8], hv[9], hv[10], hv[11]);
        }
        // ---- stage 1, chunk B (41 threads, wave 0): x from LDS ----
        if (hasB) {
            const float* p0 = &xs[(rB * XC + cB) * 3];
            const float* p1 = &xs[((rB + 1) * XC + cB) * 3];
            float4 a0 = ((const float4*)p0)[0], a1 = ((const float4*)p0)[1];
            float4 a2 = ((const float4*)p0)[2], a3 = ((const float4*)p0)[3];
            float2 a4 = ((const float2*)p0)[8];
            float4 b0 = ((const float4*)p1)[0], b1 = ((const float4*)p1)[1];
            float4 b2 = ((const float4*)p1)[2], b3 = ((const float4*)p1)[3];
            float xb0[18] = {a0.x,a0.y,a0.z,a0.w,a1.x,a1.y,a1.z,a1.w,
                             a2.x,a2.y,a2.z,a2.w,a3.x,a3.y,a3.z,a3.w,a4.x,a4.y};
            float xb1[16] = {b0.x,b0.y,b0.z,b0.w,b1.x,b1.y,b1.z,b1.w,
                             b2.x,b2.y,b2.z,b2.w,b3.x,b3.y,b3.z,b3.w};
            float pre[3][4];
            #pragma unroll
            for (int i = 0; i < 3; ++i)
                #pragma unroll
                for (int p = 0; p < 4; ++p) pre[i][p] = br[i];
            #pragma unroll
            for (int i = 0; i < 3; ++i)
            #pragma unroll
            for (int j = 0; j < 3; ++j)
            #pragma unroll
            for (int kx = 0; kx < 3; ++kx) {
                float w0 = w1r[i][j][0][kx];
                #pragma unroll
                for (int p = 0; p < 4; ++p)
                    pre[i][p] += w0 * xb0[(kx + p) * 3 + j];
                if (kx == 0 || (kx == 1 && j <= i)) {
                    float w1v = w1r[i][j][1][kx];
                    #pragma unroll
                    for (int p = 0; p < 4; ++p)
                        pre[i][p] += w1v * xb1[(kx + p) * 3 + j];
                }
            }
            float hv[12];
            #pragma unroll
            for (int p = 0; p < 4; ++p)
                #pragma unroll
                for (int i = 0; i < 3; ++i)
                    hv[p * 3 + i] = eluf(pre[i][p]) * mB[p];
            float* hrow = &hs[(rB * HC + cB) * 3];
            ((float4*)hrow)[0] = make_float4(hv[0], hv[1], hv[2],  hv[3]);
            ((float4*)hrow)[1] = make_float4(hv[4], hv[5], hv[6],  hv[7]);
            ((float4*)hrow)[2] = make_float4(hv[8], hv[9], hv[10], hv[11]);
        }

        // stage-2 weights: issue scalar loads before the barrier
        float w2r[3][3][2][3];
        #pragma unroll
        for (int i = 0; i < 3; ++i)
        #pragma unroll
        for (int j = 0; j < 3; ++j)
        #pragma unroll
        for (int ky = 0; ky < 2; ++ky)
        #pragma unroll
        for (int kx = 0; kx < 3; ++kx)
            if (ky == 0 || kx == 0 || (kx == 1 && j <= i))
                w2r[i][j][ky][kx] = wb[864 + l * WPL + i * 18 + j * 6 + ky * 3 + kx];

        __syncthreads();  // hs ready

        // ---- stage 2: acc += conv(h, w2[l]) at this thread's 1x4 outputs ----
        {
            const float* p0 = &hs[(ty * HC + tx) * 3];
            const float* p1 = &hs[((ty + 1) * HC + tx) * 3];
            float4 a0 = ((const float4*)p0)[0], a1 = ((const float4*)p0)[1];
            float4 a2 = ((const float4*)p0)[2], a3 = ((const float4*)p0)[3];
            float2 a4 = ((const float2*)p0)[8];
            float4 b0 = ((const float4*)p1)[0], b1 = ((const float4*)p1)[1];
            float4 b2 = ((const float4*)p1)[2], b3 = ((const float4*)p1)[3];
            float h0[18] = {a0.x,a0.y,a0.z,a0.w,a1.x,a1.y,a1.z,a1.w,
                            a2.x,a2.y,a2.z,a2.w,a3.x,a3.y,a3.z,a3.w,a4.x,a4.y};
            float h1[16] = {b0.x,b0.y,b0.z,b0.w,b1.x,b1.y,b1.z,b1.w,
                            b2.x,b2.y,b2.z,b2.w,b3.x,b3.y,b3.z,b3.w};
            #pragma unroll
            for (int i = 0; i < 3; ++i)
            #pragma unroll
            for (int j = 0; j < 3; ++j)
            #pragma unroll
            for (int kx = 0; kx < 3; ++kx) {
                float w0 = w2r[i][j][0][kx];
                #pragma unroll
                for (int p = 0; p < 4; ++p)
                    acc[i][p] += w0 * h0[(kx + p) * 3 + j];
                if (kx == 0 || (kx == 1 && j <= i)) {
                    float w1v = w2r[i][j][1][kx];
                    #pragma unroll
                    for (int p = 0; p < 4; ++p)
                        acc[i][p] += w1v * h1[(kx + p) * 3 + j];
                }
            }
        }
    }

    // ---- epilogue: out = acc/L + res*gate*x ----
    float rv = res[0];
    float rg = rv > 0.f ? rv : 0.f;
    const int gy = oy0 + ty;
    float* ob = out + b * NC * NH * NW;
    #pragma unroll
    for (int i = 0; i < 3; ++i) {
        float4 o;
        o.x = acc[i][0] * (1.f / 16.f) + rg * xs[((ty + 2) * XC + tx + 2 + 0) * 3 + i];
        o.y = acc[i][1] * (1.f / 16.f) + rg * xs[((ty + 2) * XC + tx + 2 + 1) * 3 + i];
        o.z = acc[i][2] * (1.f / 16.f) + rg * xs[((ty + 2) * XC + tx + 2 + 2) * 3 + i];
        o.w = acc[i][3] * (1.f / 16.f) + rg * xs[((ty + 2) * XC + tx + 2 + 3) * 3 + i];
        *(float4*)(ob + i * NH * NW + gy * NW + ox0 + tx) = o;
    }
}

extern "C" void kernel_launch(void* const* d_in, const int* in_sizes, int n_in,
                              void* d_out, int out_size, void* d_ws, size_t ws_size,
                              hipStream_t stream) {
    (void)in_sizes; (void)n_in; (void)out_size; (void)ws_size;
    const float* x   = (const float*)d_in[0];
    const float* w1  = (const float*)d_in[1];
    const float* c1  = (const float*)d_in[2];
    const float* b1  = (const float*)d_in[3];
    const float* w2  = (const float*)d_in[4];
    const float* c2  = (const float*)d_in[5];
    const float* res = (const float*)d_in[6];
    float* out = (float*)d_out;
    float* wb  = (float*)d_ws;  // 1728 floats of masked packed weights

    hipLaunchKernelGGL(prep_weights, dim3(4), dim3(256), 0, stream, w1, c1, w2, c2, wb);
    hipLaunchKernelGGL(fused_block, dim3(4, 4, 64), dim3(256), 0, stream,
                       x, b1, res, wb, out);
}

// Round 3
// 160.910 us; speedup vs baseline: 2.4549x; 2.4549x over previous
//
#include <hip/hip_runtime.h>
#include <math.h>

// BasicBlockA: masked conv (L*C out) + bias + ELU -> grouped masked conv -> mean over L + residual.
// Fully fused: one block = one 32x32 output tile of one batch image.
// Mask analysis: kernel row ky=2 is always zero; row ky=1 keeps kx=0 always and kx=1 iff j<=i.
// R3: R1 structure (no persistent register arrays -> no scratch spill; R2's 836MB FETCH was
// spill traffic). Changes vs R1: chunk indices & boundary masks precomputed once; chunk-B
// guarded by wave-uniform if(tid<41) so waves 1-3 skip via execz; LDS base pointers hoisted.

namespace {
constexpr int NC = 3, NH = 128, NW = 128, NL = 16;
constexpr int TILE = 32;
constexpr int XR = 34, XC = 40;  // x tile: rows (oy0-2 .. oy0+31), 40-col stride, 3ch interleaved
constexpr int HR = 33, HC = 36;  // h tile: rows (oy0-1 .. oy0+31), 36-col stride, 3ch interleaved
constexpr int WPL = 54;          // packed weights per latent: [i][j][ky<2][kx<3]
}

__device__ __forceinline__ float softplusf(float v) {
    return v > 20.f ? v : log1pf(expf(v));
}

// Build masked weights into d_ws: wb[0..863] = w1 packed, wb[864..1727] = w2 packed.
// Packed layout [l][i][j][ky(2)][kx(3)]; the always-masked ky==2 row is dropped.
__global__ void prep_weights(const float* __restrict__ w1, const float* __restrict__ c1,
                             const float* __restrict__ w2, const float* __restrict__ c2,
                             float* __restrict__ wb) {
    int e = blockIdx.x * blockDim.x + threadIdx.x;
    if (e >= NL * NC * NC * 2 * 3) return;
    int kx = e % 3;
    int ky = (e / 3) % 2;
    int j  = (e / 6) % 3;
    int i  = (e / 18) % 3;
    int l  = e / WPL;
    int g = l * 81 + i * 27 + j * 9 + ky * 3 + kx;  // [L,C,C,3,3] global index
    bool used   = (ky == 0) || (kx == 0) || (kx == 1 && j <= i);
    bool center = (i == j) && (ky == 1) && (kx == 1);
    wb[e]       = used ? (center ? softplusf(c1[g]) : w1[g]) : 0.f;
    wb[864 + e] = used ? (center ? softplusf(c2[g]) : w2[g]) : 0.f;
}

__device__ __forceinline__ float eluf(float v) {
    float e = __expf(v) - 1.f;
    return v > 0.f ? v : e;
}

__global__ __launch_bounds__(256, 4) void fused_block(
    const float* __restrict__ x, const float* __restrict__ bias1,
    const float* __restrict__ res, const float* __restrict__ wb,
    float* __restrict__ out)
{
    __shared__ alignas(16) float xs[XR * XC * 3];
    __shared__ alignas(16) float hs[HR * HC * 3];

    const int tid = threadIdx.x;
    const int b   = blockIdx.z;
    const int oy0 = blockIdx.y * TILE;
    const int ox0 = blockIdx.x * TILE;

    // ---- load x tile: planar (coalesced) global reads, channel-interleaved LDS store ----
    const float* xb = x + b * NC * NH * NW;
    for (int idx = tid; idx < XR * XC * 3; idx += 256) {
        int lx = idx % XC;
        int ly = (idx / XC) % XR;
        int c  = idx / (XC * XR);
        int gy = oy0 - 2 + ly, gx = ox0 - 2 + lx;
        float v = 0.f;
        if (gy >= 0 && gy < NH && gx >= 0 && gx < NW)
            v = xb[c * NH * NW + gy * NW + gx];
        xs[(ly * XC + lx) * 3 + c] = v;
    }

    // ---- precompute chunk assignment (once) ----
    // chunk A: all 256 threads; chunk B: chunks 256..296 -> tid<41 (all wave 0)
    const int rA = tid / 9;
    const int cA = (tid % 9) * 4;
    const bool hasB = (tid < HR * 9 - 256);   // 41 threads, wave 0 only
    const int rB = (tid + 256) / 9;
    const int cB = ((tid + 256) % 9) * 4;

    // boundary masks as float 0/1, computed once
    float4 mA, mB;
    {
        int gyA = oy0 - 1 + rA;
        bool ra = (gyA >= 0 && gyA < NH);
        int gyB = oy0 - 1 + rB;
        bool rb = (gyB >= 0 && gyB < NH);
        int gxA = ox0 - 1 + cA, gxB = ox0 - 1 + cB;
        mA.x = (ra && gxA + 0 >= 0 && gxA + 0 < NW) ? 1.f : 0.f;
        mA.y = (ra && gxA + 1 >= 0 && gxA + 1 < NW) ? 1.f : 0.f;
        mA.z = (ra && gxA + 2 >= 0 && gxA + 2 < NW) ? 1.f : 0.f;
        mA.w = (ra && gxA + 3 >= 0 && gxA + 3 < NW) ? 1.f : 0.f;
        mB.x = (rb && gxB + 0 >= 0 && gxB + 0 < NW) ? 1.f : 0.f;
        mB.y = (rb && gxB + 1 >= 0 && gxB + 1 < NW) ? 1.f : 0.f;
        mB.z = (rb && gxB + 2 >= 0 && gxB + 2 < NW) ? 1.f : 0.f;
        mB.w = (rb && gxB + 3 >= 0 && gxB + 3 < NW) ? 1.f : 0.f;
    }

    const int ty = tid >> 3;       // output row within tile (0..31)
    const int tx = (tid & 7) * 4;  // output col, 1x4 chunk per thread

    // hoisted LDS addresses (all 16B-aligned: 48B chunk stride, 480B row stride)
    const float* xA0 = &xs[(rA * XC + cA) * 3];
    const float* xA1 = &xs[((rA + 1) * XC + cA) * 3];
    float*       hA  = &hs[(rA * HC + cA) * 3];
    const float* xB0 = &xs[(rB * XC + cB) * 3];
    const float* xB1 = &xs[((rB + 1) * XC + cB) * 3];
    float*       hB  = &hs[(rB * HC + cB) * 3];
    const float* h20 = &hs[(ty * HC + tx) * 3];
    const float* h21 = &hs[((ty + 1) * HC + tx) * 3];

    float acc[3][4] = {{0.f}};

    #pragma unroll 1
    for (int l = 0; l < NL; ++l) {
        // stage-1 weights (uniform index -> scalar loads); only live taps read
        float w1r[3][3][2][3];
        #pragma unroll
        for (int i = 0; i < 3; ++i)
        #pragma unroll
        for (int j = 0; j < 3; ++j)
        #pragma unroll
        for (int ky = 0; ky < 2; ++ky)
        #pragma unroll
        for (int kx = 0; kx < 3; ++kx)
            if (ky == 0 || kx == 0 || (kx == 1 && j <= i))
                w1r[i][j][ky][kx] = wb[l * WPL + i * 18 + j * 6 + ky * 3 + kx];
        float br[3];
        #pragma unroll
        for (int i = 0; i < 3; ++i) br[i] = bias1[l * 3 + i];

        __syncthreads();  // prev latent's stage-2 reads done -> hs writable; xs ready at l==0

        // ---- stage 1, chunk A (all threads) ----
        {
            float4 v0 = ((const float4*)xA0)[0], v1 = ((const float4*)xA0)[1];
            float4 v2 = ((const float4*)xA0)[2], v3 = ((const float4*)xA0)[3];
            float2 v4 = ((const float2*)xA0)[8];
            float4 u0 = ((const float4*)xA1)[0], u1 = ((const float4*)xA1)[1];
            float4 u2 = ((const float4*)xA1)[2], u3 = ((const float4*)xA1)[3];
            float x0[18] = {v0.x,v0.y,v0.z,v0.w,v1.x,v1.y,v1.z,v1.w,
                            v2.x,v2.y,v2.z,v2.w,v3.x,v3.y,v3.z,v3.w,v4.x,v4.y};
            float x1[16] = {u0.x,u0.y,u0.z,u0.w,u1.x,u1.y,u1.z,u1.w,
                            u2.x,u2.y,u2.z,u2.w,u3.x,u3.y,u3.z,u3.w};
            float pre[3][4];
            #pragma unroll
            for (int i = 0; i < 3; ++i)
                #pragma unroll
                for (int p = 0; p < 4; ++p) pre[i][p] = br[i];
            #pragma unroll
            for (int i = 0; i < 3; ++i)
            #pragma unroll
            for (int j = 0; j < 3; ++j)
            #pragma unroll
            for (int kx = 0; kx < 3; ++kx) {
                float w0 = w1r[i][j][0][kx];
                #pragma unroll
                for (int p = 0; p < 4; ++p)
                    pre[i][p] += w0 * x0[(kx + p) * 3 + j];
                if (kx == 0 || (kx == 1 && j <= i)) {
                    float w1v = w1r[i][j][1][kx];
                    #pragma unroll
                    for (int p = 0; p < 4; ++p)
                        pre[i][p] += w1v * x1[(kx + p) * 3 + j];
                }
            }
            float m[4] = {mA.x, mA.y, mA.z, mA.w};
            float hv[12];
            #pragma unroll
            for (int p = 0; p < 4; ++p)
                #pragma unroll
                for (int i = 0; i < 3; ++i)
                    hv[p * 3 + i] = eluf(pre[i][p]) * m[p];
            ((float4*)hA)[0] = make_float4(hv[0], hv[1], hv[2],  hv[3]);
            ((float4*)hA)[1] = make_float4(hv[4], hv[5], hv[6],  hv[7]);
            ((float4*)hA)[2] = make_float4(hv[8], hv[9], hv[10], hv[11]);
        }
        // ---- stage 1, chunk B: tid<41, wave 0 only; waves 1-3 skip via execz ----
        if (hasB) {
            float4 v0 = ((const float4*)xB0)[0], v1 = ((const float4*)xB0)[1];
            float4 v2 = ((const float4*)xB0)[2], v3 = ((const float4*)xB0)[3];
            float2 v4 = ((const float2*)xB0)[8];
            float4 u0 = ((const float4*)xB1)[0], u1 = ((const float4*)xB1)[1];
            float4 u2 = ((const float4*)xB1)[2], u3 = ((const float4*)xB1)[3];
            float x0[18] = {v0.x,v0.y,v0.z,v0.w,v1.x,v1.y,v1.z,v1.w,
                            v2.x,v2.y,v2.z,v2.w,v3.x,v3.y,v3.z,v3.w,v4.x,v4.y};
            float x1[16] = {u0.x,u0.y,u0.z,u0.w,u1.x,u1.y,u1.z,u1.w,
                            u2.x,u2.y,u2.z,u2.w,u3.x,u3.y,u3.z,u3.w};
            float pre[3][4];
            #pragma unroll
            for (int i = 0; i < 3; ++i)
                #pragma unroll
                for (int p = 0; p < 4; ++p) pre[i][p] = br[i];
            #pragma unroll
            for (int i = 0; i < 3; ++i)
            #pragma unroll
            for (int j = 0; j < 3; ++j)
            #pragma unroll
            for (int kx = 0; kx < 3; ++kx) {
                float w0 = w1r[i][j][0][kx];
                #pragma unroll
                for (int p = 0; p < 4; ++p)
                    pre[i][p] += w0 * x0[(kx + p) * 3 + j];
                if (kx == 0 || (kx == 1 && j <= i)) {
                    float w1v = w1r[i][j][1][kx];
                    #pragma unroll
                    for (int p = 0; p < 4; ++p)
                        pre[i][p] += w1v * x1[(kx + p) * 3 + j];
                }
            }
            float m[4] = {mB.x, mB.y, mB.z, mB.w};
            float hv[12];
            #pragma unroll
            for (int p = 0; p < 4; ++p)
                #pragma unroll
                for (int i = 0; i < 3; ++i)
                    hv[p * 3 + i] = eluf(pre[i][p]) * m[p];
            ((float4*)hB)[0] = make_float4(hv[0], hv[1], hv[2],  hv[3]);
            ((float4*)hB)[1] = make_float4(hv[4], hv[5], hv[6],  hv[7]);
            ((float4*)hB)[2] = make_float4(hv[8], hv[9], hv[10], hv[11]);
        }

        // stage-2 weights: scalar loads issued before the barrier
        float w2r[3][3][2][3];
        #pragma unroll
        for (int i = 0; i < 3; ++i)
        #pragma unroll
        for (int j = 0; j < 3; ++j)
        #pragma unroll
        for (int ky = 0; ky < 2; ++ky)
        #pragma unroll
        for (int kx = 0; kx < 3; ++kx)
            if (ky == 0 || kx == 0 || (kx == 1 && j <= i))
                w2r[i][j][ky][kx] = wb[864 + l * WPL + i * 18 + j * 6 + ky * 3 + kx];

        __syncthreads();  // hs ready

        // ---- stage 2: acc += conv(h, w2[l]) at this thread's 1x4 outputs ----
        {
            float4 v0 = ((const float4*)h20)[0], v1 = ((const float4*)h20)[1];
            float4 v2 = ((const float4*)h20)[2], v3 = ((const float4*)h20)[3];
            float2 v4 = ((const float2*)h20)[8];
            float4 u0 = ((const float4*)h21)[0], u1 = ((const float4*)h21)[1];
            float4 u2 = ((const float4*)h21)[2], u3 = ((const float4*)h21)[3];
            float h0[18] = {v0.x,v0.y,v0.z,v0.w,v1.x,v1.y,v1.z,v1.w,
                            v2.x,v2.y,v2.z,v2.w,v3.x,v3.y,v3.z,v3.w,v4.x,v4.y};
            float h1[16] = {u0.x,u0.y,u0.z,u0.w,u1.x,u1.y,u1.z,u1.w,
                            u2.x,u2.y,u2.z,u2.w,u3.x,u3.y,u3.z,u3.w};
            #pragma unroll
            for (int i = 0; i < 3; ++i)
            #pragma unroll
            for (int j = 0; j < 3; ++j)
            #pragma unroll
            for (int kx = 0; kx < 3; ++kx) {
                float w0 = w2r[i][j][0][kx];
                #pragma unroll
                for (int p = 0; p < 4; ++p)
                    acc[i][p] += w0 * h0[(kx + p) * 3 + j];
                if (kx == 0 || (kx == 1 && j <= i)) {
                    float w1v = w2r[i][j][1][kx];
                    #pragma unroll
                    for (int p = 0; p < 4; ++p)
                        acc[i][p] += w1v * h1[(kx + p) * 3 + j];
                }
            }
        }
    }

    // ---- epilogue: out = acc/L + res*gate*x ----
    float rv = res[0];
    float rg = rv > 0.f ? rv : 0.f;
    const int gy = oy0 + ty;
    float* ob = out + b * NC * NH * NW;
    #pragma unroll
    for (int i = 0; i < 3; ++i) {
        float4 o;
        o.x = acc[i][0] * (1.f / 16.f) + rg * xs[((ty + 2) * XC + tx + 2 + 0) * 3 + i];
        o.y = acc[i][1] * (1.f / 16.f) + rg * xs[((ty + 2) * XC + tx + 2 + 1) * 3 + i];
        o.z = acc[i][2] * (1.f / 16.f) + rg * xs[((ty + 2) * XC + tx + 2 + 2) * 3 + i];
        o.w = acc[i][3] * (1.f / 16.f) + rg * xs[((ty + 2) * XC + tx + 2 + 3) * 3 + i];
        *(float4*)(ob + i * NH * NW + gy * NW + ox0 + tx) = o;
    }
}

extern "C" void kernel_launch(void* const* d_in, const int* in_sizes, int n_in,
                              void* d_out, int out_size, void* d_ws, size_t ws_size,
                              hipStream_t stream) {
    (void)in_sizes; (void)n_in; (void)out_size; (void)ws_size;
    const float* x   = (const float*)d_in[0];
    const float* w1  = (const float*)d_in[1];
    const float* c1  = (const float*)d_in[2];
    const float* b1  = (const float*)d_in[3];
    const float* w2  = (const float*)d_in[4];
    const float* c2  = (const float*)d_in[5];
    const float* res = (const float*)d_in[6];
    float* out = (float*)d_out;
    float* wb  = (float*)d_ws;  // 1728 floats of masked packed weights

    hipLaunchKernelGGL(prep_weights, dim3(4), dim3(256), 0, stream, w1, c1, w2, c2, wb);
    hipLaunchKernelGGL(fused_block, dim3(4, 4, 64), dim3(256), 0, stream,
                       x, b1, res, wb, out);
}

// Round 4
// 158.914 us; speedup vs baseline: 2.4858x; 1.0126x over previous
//
#include <hip/hip_runtime.h>
#include <math.h>

// BasicBlockA: masked conv (L*C out) + bias + ELU -> grouped masked conv -> mean over L + residual.
// Fully fused: one block = one 32x32 output tile of one batch image.
// Mask: kernel row ky=2 always zero; row ky=1 keeps kx=0 always and kx=1 iff j<=i (42 live taps).
// R4: stage-1 chunk map changed 9-chunks/row -> 8-chunks/row (r=tid>>3,u=tid&7) so each 8-lane
// group's ds_read_b128 bases (stride 12 words) tile all 32 banks exactly once (stage-2 already
// had this property). Edge work (h cols 32-33, h row 32) -> 41-lane wave-0 path as before.

namespace {
constexpr int NC = 3, NH = 128, NW = 128, NL = 16;
constexpr int TILE = 32;
constexpr int XR = 34, XC = 40;  // x tile: rows (oy0-2 .. oy0+31), 40-col stride, 3ch interleaved
constexpr int HR = 33, HC = 36;  // h tile: rows (oy0-1 .. oy0+31), 36-col stride, 3ch interleaved
constexpr int WPL = 54;          // packed weights per latent: [i][j][ky<2][kx<3]
}

__device__ __forceinline__ float softplusf(float v) {
    return v > 20.f ? v : log1pf(expf(v));
}

// Build masked weights into d_ws: wb[0..863] = w1 packed, wb[864..1727] = w2 packed.
__global__ void prep_weights(const float* __restrict__ w1, const float* __restrict__ c1,
                             const float* __restrict__ w2, const float* __restrict__ c2,
                             float* __restrict__ wb) {
    int e = blockIdx.x * blockDim.x + threadIdx.x;
    if (e >= NL * NC * NC * 2 * 3) return;
    int kx = e % 3;
    int ky = (e / 3) % 2;
    int j  = (e / 6) % 3;
    int i  = (e / 18) % 3;
    int l  = e / WPL;
    int g = l * 81 + i * 27 + j * 9 + ky * 3 + kx;  // [L,C,C,3,3] global index
    bool used   = (ky == 0) || (kx == 0) || (kx == 1 && j <= i);
    bool center = (i == j) && (ky == 1) && (kx == 1);
    wb[e]       = used ? (center ? softplusf(c1[g]) : w1[g]) : 0.f;
    wb[864 + e] = used ? (center ? softplusf(c2[g]) : w2[g]) : 0.f;
}

__device__ __forceinline__ float eluf(float v) {
    float e = __expf(v) - 1.f;
    return v > 0.f ? v : e;
}

__global__ __launch_bounds__(256, 4) void fused_block(
    const float* __restrict__ x, const float* __restrict__ bias1,
    const float* __restrict__ res, const float* __restrict__ wb,
    float* __restrict__ out)
{
    __shared__ alignas(16) float xs[XR * XC * 3];
    __shared__ alignas(16) float hs[HR * HC * 3];

    const int tid = threadIdx.x;
    const int b   = blockIdx.z;
    const int oy0 = blockIdx.y * TILE;
    const int ox0 = blockIdx.x * TILE;

    // ---- load x tile: planar (coalesced) global reads, channel-interleaved LDS store ----
    const float* xb = x + b * NC * NH * NW;
    for (int idx = tid; idx < XR * XC * 3; idx += 256) {
        int lx = idx % XC;
        int ly = (idx / XC) % XR;
        int c  = idx / (XC * XR);
        int gy = oy0 - 2 + ly, gx = ox0 - 2 + lx;
        float v = 0.f;
        if (gy >= 0 && gy < NH && gx >= 0 && gx < NW)
            v = xb[c * NH * NW + gy * NW + gx];
        xs[(ly * XC + lx) * 3 + c] = v;
    }

    // ---- stage-1 chunk map: A = 32 rows x 8 chunks (bank-clean); B = edge, wave 0 ----
    const int rA = tid >> 3;           // h row 0..31
    const int cA = (tid & 7) * 4;      // h col 0..28 step 4
    const bool hasB = (tid < 41);      // wave 0 only
    const int rB = (tid < 33) ? tid : 32;
    const int cB = (tid < 33) ? 32 : (tid - 33) * 4;

    // boundary masks as float 0/1, computed once
    float4 mA, mB;
    {
        int gyA = oy0 - 1 + rA;
        bool ra = (gyA >= 0 && gyA < NH);
        int gyB = oy0 - 1 + rB;
        bool rb = (gyB >= 0 && gyB < NH);
        int gxA = ox0 - 1 + cA, gxB = ox0 - 1 + cB;
        mA.x = (ra && gxA + 0 >= 0 && gxA + 0 < NW) ? 1.f : 0.f;
        mA.y = (ra && gxA + 1 >= 0 && gxA + 1 < NW) ? 1.f : 0.f;
        mA.z = (ra && gxA + 2 >= 0 && gxA + 2 < NW) ? 1.f : 0.f;
        mA.w = (ra && gxA + 3 >= 0 && gxA + 3 < NW) ? 1.f : 0.f;
        mB.x = (rb && gxB + 0 >= 0 && gxB + 0 < NW) ? 1.f : 0.f;
        mB.y = (rb && gxB + 1 >= 0 && gxB + 1 < NW) ? 1.f : 0.f;
        mB.z = (rb && gxB + 2 >= 0 && gxB + 2 < NW) ? 1.f : 0.f;
        mB.w = (rb && gxB + 3 >= 0 && gxB + 3 < NW) ? 1.f : 0.f;
    }

    const int ty = tid >> 3;       // output row within tile (0..31)
    const int tx = (tid & 7) * 4;  // output col, 1x4 chunk per thread

    // hoisted LDS addresses (all 16B-aligned: 48B chunk stride, rows mult of 16B)
    const float* xA0 = &xs[(rA * XC + cA) * 3];
    const float* xA1 = &xs[((rA + 1) * XC + cA) * 3];
    float*       hA  = &hs[(rA * HC + cA) * 3];
    const float* xB0 = &xs[(rB * XC + cB) * 3];
    const float* xB1 = &xs[((rB + 1) * XC + cB) * 3];
    float*       hB  = &hs[(rB * HC + cB) * 3];
    const float* h20 = &hs[(ty * HC + tx) * 3];
    const float* h21 = &hs[((ty + 1) * HC + tx) * 3];

    float acc[3][4] = {{0.f}};

    #pragma unroll 1
    for (int l = 0; l < NL; ++l) {
        // stage-1 weights (uniform index -> scalar loads); only live taps read
        float w1r[3][3][2][3];
        #pragma unroll
        for (int i = 0; i < 3; ++i)
        #pragma unroll
        for (int j = 0; j < 3; ++j)
        #pragma unroll
        for (int ky = 0; ky < 2; ++ky)
        #pragma unroll
        for (int kx = 0; kx < 3; ++kx)
            if (ky == 0 || kx == 0 || (kx == 1 && j <= i))
                w1r[i][j][ky][kx] = wb[l * WPL + i * 18 + j * 6 + ky * 3 + kx];
        float br[3];
        #pragma unroll
        for (int i = 0; i < 3; ++i) br[i] = bias1[l * 3 + i];

        __syncthreads();  // prev latent's stage-2 reads done -> hs writable; xs ready at l==0

        // ---- stage 1, chunk A (all threads) ----
        {
            float4 v0 = ((const float4*)xA0)[0], v1 = ((const float4*)xA0)[1];
            float4 v2 = ((const float4*)xA0)[2], v3 = ((const float4*)xA0)[3];
            float2 v4 = ((const float2*)xA0)[8];
            float4 u0 = ((const float4*)xA1)[0], u1 = ((const float4*)xA1)[1];
            float4 u2 = ((const float4*)xA1)[2], u3 = ((const float4*)xA1)[3];
            float x0[18] = {v0.x,v0.y,v0.z,v0.w,v1.x,v1.y,v1.z,v1.w,
                            v2.x,v2.y,v2.z,v2.w,v3.x,v3.y,v3.z,v3.w,v4.x,v4.y};
            float x1[16] = {u0.x,u0.y,u0.z,u0.w,u1.x,u1.y,u1.z,u1.w,
                            u2.x,u2.y,u2.z,u2.w,u3.x,u3.y,u3.z,u3.w};
            float pre[3][4];
            #pragma unroll
            for (int i = 0; i < 3; ++i)
                #pragma unroll
                for (int p = 0; p < 4; ++p) pre[i][p] = br[i];
            #pragma unroll
            for (int i = 0; i < 3; ++i)
            #pragma unroll
            for (int j = 0; j < 3; ++j)
            #pragma unroll
            for (int kx = 0; kx < 3; ++kx) {
                float w0 = w1r[i][j][0][kx];
                #pragma unroll
                for (int p = 0; p < 4; ++p)
                    pre[i][p] += w0 * x0[(kx + p) * 3 + j];
                if (kx == 0 || (kx == 1 && j <= i)) {
                    float w1v = w1r[i][j][1][kx];
                    #pragma unroll
                    for (int p = 0; p < 4; ++p)
                        pre[i][p] += w1v * x1[(kx + p) * 3 + j];
                }
            }
            float m[4] = {mA.x, mA.y, mA.z, mA.w};
            float hv[12];
            #pragma unroll
            for (int p = 0; p < 4; ++p)
                #pragma unroll
                for (int i = 0; i < 3; ++i)
                    hv[p * 3 + i] = eluf(pre[i][p]) * m[p];
            ((float4*)hA)[0] = make_float4(hv[0], hv[1], hv[2],  hv[3]);
            ((float4*)hA)[1] = make_float4(hv[4], hv[5], hv[6],  hv[7]);
            ((float4*)hA)[2] = make_float4(hv[8], hv[9], hv[10], hv[11]);
        }
        // ---- stage 1, chunk B: tid<41, wave 0 only; other waves skip via execz ----
        if (hasB) {
            float4 v0 = ((const float4*)xB0)[0], v1 = ((const float4*)xB0)[1];
            float4 v2 = ((const float4*)xB0)[2], v3 = ((const float4*)xB0)[3];
            float2 v4 = ((const float2*)xB0)[8];
            float4 u0 = ((const float4*)xB1)[0], u1 = ((const float4*)xB1)[1];
            float4 u2 = ((const float4*)xB1)[2], u3 = ((const float4*)xB1)[3];
            float x0[18] = {v0.x,v0.y,v0.z,v0.w,v1.x,v1.y,v1.z,v1.w,
                            v2.x,v2.y,v2.z,v2.w,v3.x,v3.y,v3.z,v3.w,v4.x,v4.y};
            float x1[16] = {u0.x,u0.y,u0.z,u0.w,u1.x,u1.y,u1.z,u1.w,
                            u2.x,u2.y,u2.z,u2.w,u3.x,u3.y,u3.z,u3.w};
            float pre[3][4];
            #pragma unroll
            for (int i = 0; i < 3; ++i)
                #pragma unroll
                for (int p = 0; p < 4; ++p) pre[i][p] = br[i];
            #pragma unroll
            for (int i = 0; i < 3; ++i)
            #pragma unroll
            for (int j = 0; j < 3; ++j)
            #pragma unroll
            for (int kx = 0; kx < 3; ++kx) {
                float w0 = w1r[i][j][0][kx];
                #pragma unroll
                for (int p = 0; p < 4; ++p)
                    pre[i][p] += w0 * x0[(kx + p) * 3 + j];
                if (kx == 0 || (kx == 1 && j <= i)) {
                    float w1v = w1r[i][j][1][kx];
                    #pragma unroll
                    for (int p = 0; p < 4; ++p)
                        pre[i][p] += w1v * x1[(kx + p) * 3 + j];
                }
            }
            float m[4] = {mB.x, mB.y, mB.z, mB.w};
            float hv[12];
            #pragma unroll
            for (int p = 0; p < 4; ++p)
                #pragma unroll
                for (int i = 0; i < 3; ++i)
                    hv[p * 3 + i] = eluf(pre[i][p]) * m[p];
            ((float4*)hB)[0] = make_float4(hv[0], hv[1], hv[2],  hv[3]);
            ((float4*)hB)[1] = make_float4(hv[4], hv[5], hv[6],  hv[7]);
            ((float4*)hB)[2] = make_float4(hv[8], hv[9], hv[10], hv[11]);
        }

        // stage-2 weights: scalar loads issued before the barrier
        float w2r[3][3][2][3];
        #pragma unroll
        for (int i = 0; i < 3; ++i)
        #pragma unroll
        for (int j = 0; j < 3; ++j)
        #pragma unroll
        for (int ky = 0; ky < 2; ++ky)
        #pragma unroll
        for (int kx = 0; kx < 3; ++kx)
            if (ky == 0 || kx == 0 || (kx == 1 && j <= i))
                w2r[i][j][ky][kx] = wb[864 + l * WPL + i * 18 + j * 6 + ky * 3 + kx];

        __syncthreads();  // hs ready

        // ---- stage 2: acc += conv(h, w2[l]) at this thread's 1x4 outputs ----
        {
            float4 v0 = ((const float4*)h20)[0], v1 = ((const float4*)h20)[1];
            float4 v2 = ((const float4*)h20)[2], v3 = ((const float4*)h20)[3];
            float2 v4 = ((const float2*)h20)[8];
            float4 u0 = ((const float4*)h21)[0], u1 = ((const float4*)h21)[1];
            float4 u2 = ((const float4*)h21)[2], u3 = ((const float4*)h21)[3];
            float h0[18] = {v0.x,v0.y,v0.z,v0.w,v1.x,v1.y,v1.z,v1.w,
                            v2.x,v2.y,v2.z,v2.w,v3.x,v3.y,v3.z,v3.w,v4.x,v4.y};
            float h1[16] = {u0.x,u0.y,u0.z,u0.w,u1.x,u1.y,u1.z,u1.w,
                            u2.x,u2.y,u2.z,u2.w,u3.x,u3.y,u3.z,u3.w};
            #pragma unroll
            for (int i = 0; i < 3; ++i)
            #pragma unroll
            for (int j = 0; j < 3; ++j)
            #pragma unroll
            for (int kx = 0; kx < 3; ++kx) {
                float w0 = w2r[i][j][0][kx];
                #pragma unroll
                for (int p = 0; p < 4; ++p)
                    acc[i][p] += w0 * h0[(kx + p) * 3 + j];
                if (kx == 0 || (kx == 1 && j <= i)) {
                    float w1v = w2r[i][j][1][kx];
                    #pragma unroll
                    for (int p = 0; p < 4; ++p)
                        acc[i][p] += w1v * h1[(kx + p) * 3 + j];
                }
            }
        }
    }

    // ---- epilogue: out = acc/L + res*gate*x ----
    float rv = res[0];
    float rg = rv > 0.f ? rv : 0.f;
    const int gy = oy0 + ty;
    float* ob = out + b * NC * NH * NW;
    #pragma unroll
    for (int i = 0; i < 3; ++i) {
        float4 o;
        o.x = acc[i][0] * (1.f / 16.f) + rg * xs[((ty + 2) * XC + tx + 2 + 0) * 3 + i];
        o.y = acc[i][1] * (1.f / 16.f) + rg * xs[((ty + 2) * XC + tx + 2 + 1) * 3 + i];
        o.z = acc[i][2] * (1.f / 16.f) + rg * xs[((ty + 2) * XC + tx + 2 + 2) * 3 + i];
        o.w = acc[i][3] * (1.f / 16.f) + rg * xs[((ty + 2) * XC + tx + 2 + 3) * 3 + i];
        *(float4*)(ob + i * NH * NW + gy * NW + ox0 + tx) = o;
    }
}

extern "C" void kernel_launch(void* const* d_in, const int* in_sizes, int n_in,
                              void* d_out, int out_size, void* d_ws, size_t ws_size,
                              hipStream_t stream) {
    (void)in_sizes; (void)n_in; (void)out_size; (void)ws_size;
    const float* x   = (const float*)d_in[0];
    const float* w1  = (const float*)d_in[1];
    const float* c1  = (const float*)d_in[2];
    const float* b1  = (const float*)d_in[3];
    const float* w2  = (const float*)d_in[4];
    const float* c2  = (const float*)d_in[5];
    const float* res = (const float*)d_in[6];
    float* out = (float*)d_out;
    float* wb  = (float*)d_ws;  // 1728 floats of masked packed weights

    hipLaunchKernelGGL(prep_weights, dim3(4), dim3(256), 0, stream, w1, c1, w2, c2, wb);
    hipLaunchKernelGGL(fused_block, dim3(4, 4, 64), dim3(256), 0, stream,
                       x, b1, res, wb, out);
}